// Round 4
// baseline (131.525 us; speedup 1.0000x reference)
//
#include <hip/hip_runtime.h>
#include <math.h>

// Problem constants
#define LSEQ   512
#define DDIM   1024
#define KDIM   256       // SSIZE
#define COLS   256       // LATENT
#define ROWS   4096      // B * NTOK * NSEC
#define COEF   0.1f

#define TRB    8         // rows per block; 512 blocks = 2/CU = 8 waves/CU

// Semantics collapse (verified R1-R3, absmax 3.9e-3): M = inverse(C) and the
// band mask is constant along the transformed (batch) axis, so the spectral
// chain reduces to  out[row,o] = tanh( scale(row)*dot(enc_row, W[o,:]) + b[o] ).
//
// R4 structure: thread t owns column t. A-row values are BLOCK-UNIFORM ->
// scalar (SMEM) loads feeding v_fmac_f32's SGPR operand; W comes pre-transposed
// (Wt4[k4][o][4]) as one coalesced dwordx4 per 4k phase. No LDS in the hot loop
// -> the CU-shared LDS pipe (R3's bottleneck) is idle; FMA-issue-bound.

__device__ __forceinline__ float tanh_fast(float x) {
    // 1 - 2/(e^{2x}+1): exact +/-inf limits, ~1e-6 abs err via v_exp_f32
    return 1.0f - 2.0f / (__expf(2.0f * x) + 1.0f);
}

// W[o][k] (256x256) -> Wt4[k4][o][j] = W[o][4*k4+j]; coalesced both sides via LDS tile.
__global__ __launch_bounds__(256, 4)
void transpose_w4_kernel(const float* __restrict__ W, float* __restrict__ Wt4) {
    __shared__ float tile[32][33];
    const int t  = threadIdx.x;
    const int bx = blockIdx.x;        // k-tile (32 k)
    const int by = blockIdx.y;        // o-tile (32 o)
    #pragma unroll
    for (int i = 0; i < 4; ++i) {
        const int e   = t + i * 256;        // 0..1023
        const int o_l = e >> 5;             // 0..31
        const int k_l = e & 31;             // 0..31 (consecutive per lane-group)
        tile[o_l][k_l] = W[(size_t)(by * 32 + o_l) * KDIM + bx * 32 + k_l];
    }
    __syncthreads();
    const int k4_l = t >> 5;                // 0..7
    const int o_l  = t & 31;                // 0..31
    float4 v;
    v.x = tile[o_l][4 * k4_l + 0];
    v.y = tile[o_l][4 * k4_l + 1];
    v.z = tile[o_l][4 * k4_l + 2];
    v.w = tile[o_l][4 * k4_l + 3];
    // flat float index: k4*1024 + o*4 + j ; lanes consecutive o -> coalesced x4
    *(float4*)&Wt4[(size_t)(bx * 8 + k4_l) * 1024 + (size_t)(by * 32 + o_l) * 4] = v;
}

__global__ __launch_bounds__(256, 2)
void spectral_gemm_kernel(const float* __restrict__ enc,
                          const float* __restrict__ Wt4,
                          const float* __restrict__ bias,
                          float* __restrict__ out) {
    const int t    = threadIdx.x;                 // owned column
    const int row0 = blockIdx.x * TRB;            // 8 consecutive rows (8|128: no segment straddle)

    // block-uniform A base: enc[b, l, n, :] for row = ((b*32+l)*4+n)
    const float* __restrict__ abase = enc + (size_t)(row0 >> 7) * (size_t)(LSEQ * DDIM)
                                          + (size_t)(row0 & 127) * KDIM;
    const float* __restrict__ wbase = Wt4 + (size_t)t * 4;

    float acc[TRB] = {0.f, 0.f, 0.f, 0.f, 0.f, 0.f, 0.f, 0.f};

    // ---- software pipeline: 1 phase ahead. Phase p covers k = 4p..4p+3. ----
    float4 w = *(const float4*)(wbase);           // Wt4[0][t][:]
    float4 a[TRB];
    #pragma unroll
    for (int r = 0; r < TRB; ++r)
        a[r] = *(const float4*)(abase + r * KDIM);   // uniform -> s_load

    #pragma unroll 4
    for (int p = 0; p < 64; ++p) {
        // prefetch phase p+1 (p=63 prefetch is OOB-harmless: Wt4 sits in the
        // 256MB ws, enc read lands in the next valid row)
        const float4 wn = *(const float4*)(wbase + (size_t)(p + 1) * 1024);
        float4 an[TRB];
        #pragma unroll
        for (int r = 0; r < TRB; ++r)
            an[r] = *(const float4*)(abase + r * KDIM + (p + 1) * 4);

        #pragma unroll
        for (int r = 0; r < TRB; ++r) {
            acc[r] += a[r].x * w.x;
            acc[r] += a[r].y * w.y;
            acc[r] += a[r].z * w.z;
            acc[r] += a[r].w * w.w;
        }
        w = wn;
        #pragma unroll
        for (int r = 0; r < TRB; ++r) a[r] = an[r];
    }

    // ---- epilogue: per-row scale, bias, tanh; lanes = consecutive cols ----
    const float b = bias[t];
    #pragma unroll
    for (int r = 0; r < TRB; ++r) {
        const int row = row0 + r;
        const int n = row & 3;
        const int l = (row >> 2) & 31;
        const float scale = (n == 0 || (n == 1 && l >= 16)) ? 1.0f : COEF;
        out[(size_t)row * COLS + t] = tanh_fast(scale * acc[r] + b);
    }
}

extern "C" void kernel_launch(void* const* d_in, const int* in_sizes, int n_in,
                              void* d_out, int out_size, void* d_ws, size_t ws_size,
                              hipStream_t stream) {
    const float* enc  = (const float*)d_in[0];   // [32, 512, 1024]
    const float* W    = (const float*)d_in[1];   // [256, 256]
    const float* bias = (const float*)d_in[2];   // [256]
    float* out = (float*)d_out;                  // [32, 32, 4, 256]
    float* Wt4 = (float*)d_ws;                   // [64][256][4] rearranged W

    transpose_w4_kernel<<<dim3(8, 8), dim3(256), 0, stream>>>(W, Wt4);
    spectral_gemm_kernel<<<dim3(ROWS / TRB), dim3(256), 0, stream>>>(enc, Wt4, bias, out);
}

// Round 5
// 127.054 us; speedup vs baseline: 1.0352x; 1.0352x over previous
//
#include <hip/hip_runtime.h>
#include <math.h>

// Problem constants
#define LSEQ   512
#define DDIM   1024
#define KDIM   256       // SSIZE
#define COLS   256       // LATENT
#define ROWS   4096      // B * NTOK * NSEC
#define COEF   0.1f

#define TRB    64        // rows per block (lane = local row)
#define TCB    32        // cols per block (4 waves x 8 cols)

// Semantics collapse (verified R1-R4, absmax 3.9e-3): M = inverse(C) and the
// band mask is constant along the transformed (batch) axis, so the spectral
// chain reduces to  out[row,o] = tanh( scale(row)*dot(enc_row, W[o,:]) + b[o] ).
//
// R5 structure: lane = row (A per-lane from LDS, ONE ds_read_b128 per 4k),
// wave = col-group of 8 (W wave-uniform -> s_load on the scalar pipe, which is
// otherwise idle; W slice is scalar-cache hot since 64 blocks share it).
// LDS pipe load: 8 waves x 12cyc = 96 cyc/CU per 4k vs 128 cyc FMA -> FMA-bound.

__device__ __forceinline__ float tanh_fast(float x) {
    // 1 - 2/(e^{2x}+1): exact +/-inf limits, ~1e-6 abs err via v_exp_f32
    return 1.0f - 2.0f / (__expf(2.0f * x) + 1.0f);
}

__global__ __launch_bounds__(256, 2)
void spectral_gemm_kernel(const float* __restrict__ enc,
                          const float* __restrict__ W,
                          const float* __restrict__ bias,
                          float* __restrict__ out) {
    // 64 rows x 256 k, exactly 64 KB. Physical k4 slot = k4 ^ (row & 15):
    // both staging writes and lane-row reads land 8-per-bank balanced = b128 floor.
    __shared__ float As[TRB * KDIM];

    const int t      = threadIdx.x;
    const int tile_r = blockIdx.x * TRB;   // 64 | 128 -> no batch-segment straddle
    const int tile_c = blockIdx.y * TCB;

    // ---- stage A once: rows tile_r..+63 are one contiguous 64 KB span ----
    const float* srcA = enc + (size_t)(tile_r >> 7) * (size_t)(LSEQ * DDIM)
                            + (size_t)(tile_r & 127) * KDIM;
    #pragma unroll
    for (int i = 0; i < 16; ++i) {
        const int f  = t + i * 256;        // float4 id 0..4095 (coalesced reads)
        const int r  = f >> 6;             // local row (constant per wave-instr)
        const int k4 = f & 63;
        const float4 v = *(const float4*)(srcA + (size_t)f * 4);
        *(float4*)&As[r * KDIM + ((k4 ^ (r & 15)) << 2)] = v;
    }
    __syncthreads();

    const int lane = t & 63;                                   // owned local row
    const int cg   = __builtin_amdgcn_readfirstlane(t >> 6);   // wave col-group (SGPR)
    const float* __restrict__ Wp   = W + (size_t)(tile_c + cg * 8) * KDIM;
    const float* __restrict__ arow = As + lane * KDIM;
    const int swz = lane & 15;

    float acc[8] = {0.f,0.f,0.f,0.f,0.f,0.f,0.f,0.f};

    // ---- inner: per 4k phase = 1 ds_read_b128 + 8 scalar dwordx4 + 32 v_fmac ----
    #pragma unroll 4
    for (int p = 0; p < 64; ++p) {
        const float4 a = *(const float4*)(arow + ((p ^ swz) << 2));
        #pragma unroll
        for (int c = 0; c < 8; ++c) {
            const float4 w = *(const float4*)(Wp + c * KDIM + p * 4);  // uniform -> s_load
            acc[c] += a.x * w.x;
            acc[c] += a.y * w.y;
            acc[c] += a.z * w.z;
            acc[c] += a.w * w.w;
        }
    }

    // ---- epilogue: per-row scale, bias, tanh; 2 float4 stores/thread ----
    const int row = tile_r + lane;
    const int n = row & 3;
    const int l = (row >> 2) & 31;
    const float scale = (n == 0 || (n == 1 && l >= 16)) ? 1.0f : COEF;
    float o[8];
    #pragma unroll
    for (int c = 0; c < 8; ++c)
        o[c] = tanh_fast(scale * acc[c] + bias[tile_c + cg * 8 + c]);
    float4* outp = (float4*)(out + (size_t)row * COLS + tile_c + cg * 8);
    outp[0] = make_float4(o[0], o[1], o[2], o[3]);
    outp[1] = make_float4(o[4], o[5], o[6], o[7]);
}

extern "C" void kernel_launch(void* const* d_in, const int* in_sizes, int n_in,
                              void* d_out, int out_size, void* d_ws, size_t ws_size,
                              hipStream_t stream) {
    const float* enc  = (const float*)d_in[0];   // [32, 512, 1024]
    const float* W    = (const float*)d_in[1];   // [256, 256]
    const float* bias = (const float*)d_in[2];   // [256]
    float* out = (float*)d_out;                  // [32, 32, 4, 256]

    dim3 grid(ROWS / TRB, COLS / TCB);           // 64 x 8 = 512 blocks
    spectral_gemm_kernel<<<grid, dim3(256), 0, stream>>>(enc, W, bias, out);
}

// Round 6
// 101.069 us; speedup vs baseline: 1.3013x; 1.2571x over previous
//
#include <hip/hip_runtime.h>
#include <math.h>

// Problem constants
#define LSEQ   512
#define DDIM   1024
#define KDIM   256       // SSIZE (K)
#define COLS   256       // LATENT
#define ROWS   4096      // B * NTOK * NSEC
#define COEF   0.1f

#define TR     64        // rows per block
#define TC     64        // cols per block
#define BK     128       // K phase (2 phases)

// Semantics collapse (verified R1-R5, absmax 3.9e-3): M = inverse(C) and the
// band mask is constant along the transformed (batch) axis, so the spectral
// chain reduces to  out[row,o] = tanh( scale(row)*dot(enc_row, W[o,:]) + b[o] ).
//
// R6: LDS-LDS fp32 GEMM at the fp32 floor. Ratio 0.125 b128/FMA (4x4 microtile)
// = 10.2 us LDS-pipe bound; 3 barriers total; XOR-swizzled 64KB LDS (no pad,
// no transpose staging, conflict-free reads). Known-bad paths: global/scalar W
// in inner loop (R4/R5: 45-47us), 2x4 microtile (R3: ratio 0.1875, ~20us).

__device__ __forceinline__ float tanh_fast(float x) {
    // 1 - 2/(e^{2x}+1): exact +/-inf limits, ~1e-6 abs err via v_exp_f32
    return 1.0f - 2.0f / (__expf(2.0f * x) + 1.0f);
}

__global__ __launch_bounds__(256, 1)
void spectral_gemm_kernel(const float* __restrict__ enc,
                          const float* __restrict__ W,
                          const float* __restrict__ bias,
                          float* __restrict__ out) {
    // [r][phys_k4] as float4, phys_k4 = k4 ^ ((r>>2)&7). 2 x 32 KB = 64 KB.
    __shared__ float4 As[TR * (BK / 4)];
    __shared__ float4 Ws[TC * (BK / 4)];

    const int t      = threadIdx.x;
    const int tile_r = blockIdx.x * TR;    // 64 | 128: no batch-segment straddle
    const int tile_c = blockIdx.y * TC;

    // A-tile rows tile_r..+63 are one contiguous 64 KB span of enc
    const float4* __restrict__ srcA =
        (const float4*)(enc + (size_t)(tile_r >> 7) * (size_t)(LSEQ * DDIM)
                            + (size_t)(tile_r & 127) * KDIM);
    const float4* __restrict__ srcW = (const float4*)(W + (size_t)tile_c * KDIM);

    const int tx = t & 15, ty = t >> 4;
    const int sA = ty & 7;        // per-thread swizzle key for its 4 A rows
    const int sW = tx & 7;        // per-thread swizzle key for its 4 W cols
    const int ra = ty * 4;        // local row base  (rows ra..ra+3)
    const int ca = tx * 4;        // local col base  (cols ca..ca+3)

    float acc[4][4] = {{0.f,0.f,0.f,0.f},{0.f,0.f,0.f,0.f},
                       {0.f,0.f,0.f,0.f},{0.f,0.f,0.f,0.f}};

    for (int p = 0; p < 2; ++p) {
        if (p) __syncthreads();            // finish phase-0 reads before overwrite

        // ---- stage both tiles: contiguous coalesced reads, permuted-contig
        //      b128 LDS writes (conflict-free) ----
        #pragma unroll
        for (int i = 0; i < 8; ++i) {
            const int f    = t + i * 256;          // float4 id 0..2047
            const int r    = f >> 5;               // local row/col (32 f4 per row)
            const int k4   = f & 31;
            const int phys = k4 ^ ((r >> 2) & 7);
            As[r * 32 + phys] = srcA[r * 64 + 32 * p + k4];
            Ws[r * 32 + phys] = srcW[r * 64 + 32 * p + k4];
        }
        __syncthreads();

        // ---- inner: per 4k = 8 ds_read_b128 + 2 v_xor + 64 v_fmac ----
        #pragma unroll 8
        for (int k4 = 0; k4 < 32; ++k4) {
            const int pa = k4 ^ sA;
            const int pw = k4 ^ sW;
            float4 a[4], w[4];
            #pragma unroll
            for (int i = 0; i < 4; ++i) a[i] = As[(ra + i) * 32 + pa];
            #pragma unroll
            for (int j = 0; j < 4; ++j) w[j] = Ws[(ca + j) * 32 + pw];
            #pragma unroll
            for (int i = 0; i < 4; ++i)
                #pragma unroll
                for (int j = 0; j < 4; ++j) {
                    acc[i][j] += a[i].x * w[j].x;
                    acc[i][j] += a[i].y * w[j].y;
                    acc[i][j] += a[i].z * w[j].z;
                    acc[i][j] += a[i].w * w[j].w;
                }
        }
    }

    // ---- epilogue: per-row scale, bias, tanh; coalesced float4 stores ----
    const float4 b4 = *(const float4*)&bias[tile_c + ca];
    #pragma unroll
    for (int i = 0; i < 4; ++i) {
        const int row = tile_r + ra + i;
        const int n = row & 3;
        const int l = (row >> 2) & 31;
        const float scale = (n == 0 || (n == 1 && l >= 16)) ? 1.0f : COEF;
        float4 o;
        o.x = tanh_fast(scale * acc[i][0] + b4.x);
        o.y = tanh_fast(scale * acc[i][1] + b4.y);
        o.z = tanh_fast(scale * acc[i][2] + b4.z);
        o.w = tanh_fast(scale * acc[i][3] + b4.w);
        *(float4*)&out[(size_t)row * COLS + tile_c + ca] = o;
    }
}

extern "C" void kernel_launch(void* const* d_in, const int* in_sizes, int n_in,
                              void* d_out, int out_size, void* d_ws, size_t ws_size,
                              hipStream_t stream) {
    const float* enc  = (const float*)d_in[0];   // [32, 512, 1024]
    const float* W    = (const float*)d_in[1];   // [256, 256]
    const float* bias = (const float*)d_in[2];   // [256]
    float* out = (float*)d_out;                  // [32, 32, 4, 256]

    dim3 grid(ROWS / TR, COLS / TC);             // 64 x 4 = 256 blocks (1/CU)
    spectral_gemm_kernel<<<grid, dim3(256), 0, stream>>>(enc, W, bias, out);
}

// Round 7
// 93.718 us; speedup vs baseline: 1.4034x; 1.0784x over previous
//
#include <hip/hip_runtime.h>
#include <math.h>

// Problem constants
#define LSEQ   512
#define DDIM   1024
#define KDIM   256       // K
#define COLS   256       // LATENT
#define ROWS   4096      // B * NTOK * NSEC
#define COEF   0.1f

// Tiling: block 32 rows x 64 cols, 4 waves, wave = 16x32 strip (2 MFMA tiles).
// K in 2 phases of 128. Grid 128x4 = 512 blocks = 2/CU = 8 waves/CU (2/SIMD).
#define TR     32
#define TC     64
#define BK     128
#define RSTR   128       // LDS row stride in shorts (= BK bf16 = 256 B, no pad)

// Semantics collapse (verified R1-R6, absmax 3.9e-3): the spectral chain
// reduces to out[row,o] = tanh( scale(row)*dot(enc_row, W[o,:]) + b[o] ).
//
// R7: split-bf16 MFMA. x = hi + lo (Dekker split, each bf16); 3 passes
// ah*bh + ah*bl + al*bh -> ~2^-16 relative error, far under the 2e-2 threshold.
// LDS layout: 16-B slot = one 8-bf16 MFMA fragment; phys_slot = slot ^ (row&15)
// -> conflict-free b128 reads AND writes with zero padding (48 KB total).
// Known-bad paths: fp32 LDS-LDS (~19.6us, LDS-pipe bound); global/scalar W in
// inner loop (R4/R5, 45-47us); 1 wave/SIMD configs (R6 lesson).

typedef __attribute__((ext_vector_type(8))) short short8;    // 8 bf16 = 4 VGPRs
typedef __attribute__((ext_vector_type(4))) float float4v;   // MFMA C/D

__device__ __forceinline__ float tanh_fast(float x) {
    // 1 - 2/(e^{2x}+1): exact +/-inf limits, ~1e-6 abs err via v_exp_f32
    return 1.0f - 2.0f / (__expf(2.0f * x) + 1.0f);
}

__device__ __forceinline__ void split_bf16(float x, unsigned short& h, unsigned short& l) {
    union { float f; unsigned u; } a, hb, rb;
    a.f = x;
    const unsigned hu = (a.u + 0x7fffu + ((a.u >> 16) & 1u)) & 0xffff0000u;  // RNE
    h = (unsigned short)(hu >> 16);
    hb.u = hu;
    rb.f = x - hb.f;                                                          // exact-ish residual
    l = (unsigned short)((rb.u + 0x7fffu + ((rb.u >> 16) & 1u)) >> 16);
}

__global__ __launch_bounds__(256, 2)
void spectral_mfma_kernel(const float* __restrict__ enc,
                          const float* __restrict__ W,
                          const float* __restrict__ bias,
                          float* __restrict__ out) {
    __shared__ short Ah[TR * RSTR], Al[TR * RSTR];   // 8 KB each
    __shared__ short Wh[TC * RSTR], Wl[TC * RSTR];   // 16 KB each  -> 48 KB

    const int t      = threadIdx.x;
    const int tile_r = blockIdx.x * TR;     // 32 | 128: no batch-segment straddle
    const int tile_c = blockIdx.y * TC;

    const float* __restrict__ srcA = enc + (size_t)(tile_r >> 7) * (size_t)(LSEQ * DDIM)
                                         + (size_t)(tile_r & 127) * KDIM;
    const float* __restrict__ srcW = W + (size_t)tile_c * KDIM;

    const int lane = t & 63;
    const int wv   = t >> 6;
    const int m0   = (wv & 1) * 16;         // wave row offset in tile
    const int n0   = (wv >> 1) * 32;        // wave col offset in tile
    const int fm   = lane & 15;             // frag row/col AND swizzle key
    const int kq   = lane >> 4;             // 0..3 (k-quad)

    float4v acc0 = {0.f, 0.f, 0.f, 0.f};
    float4v acc1 = {0.f, 0.f, 0.f, 0.f};

    for (int p = 0; p < 2; ++p) {
        if (p) __syncthreads();             // drain phase-0 reads before overwrite

        // ---- stage A: 32 rows x 16 slots (8 floats each) = 512 slots ----
        #pragma unroll
        for (int i = 0; i < 2; ++i) {
            const int q = t + i * 256;
            const int r = q >> 4, s = q & 15;
            const float* g = srcA + (size_t)r * KDIM + p * BK + s * 8;
            const float4 x0 = *(const float4*)g;
            const float4 x1 = *(const float4*)(g + 4);
            const float xs[8] = {x0.x, x0.y, x0.z, x0.w, x1.x, x1.y, x1.z, x1.w};
            unsigned short h[8], l[8];
            #pragma unroll
            for (int j = 0; j < 8; ++j) split_bf16(xs[j], h[j], l[j]);
            const int phys = (s ^ (r & 15)) * 8;
            short8 hv, lv;
            #pragma unroll
            for (int j = 0; j < 8; ++j) { hv[j] = (short)h[j]; lv[j] = (short)l[j]; }
            *(short8*)&Ah[r * RSTR + phys] = hv;
            *(short8*)&Al[r * RSTR + phys] = lv;
        }
        // ---- stage W: 64 rows x 16 slots = 1024 slots ----
        #pragma unroll
        for (int i = 0; i < 4; ++i) {
            const int q = t + i * 256;
            const int r = q >> 4, s = q & 15;
            const float* g = srcW + (size_t)r * KDIM + p * BK + s * 8;
            const float4 x0 = *(const float4*)g;
            const float4 x1 = *(const float4*)(g + 4);
            const float xs[8] = {x0.x, x0.y, x0.z, x0.w, x1.x, x1.y, x1.z, x1.w};
            unsigned short h[8], l[8];
            #pragma unroll
            for (int j = 0; j < 8; ++j) split_bf16(xs[j], h[j], l[j]);
            const int phys = (s ^ (r & 15)) * 8;
            short8 hv, lv;
            #pragma unroll
            for (int j = 0; j < 8; ++j) { hv[j] = (short)h[j]; lv[j] = (short)l[j]; }
            *(short8*)&Wh[r * RSTR + phys] = hv;
            *(short8*)&Wl[r * RSTR + phys] = lv;
        }
        __syncthreads();

        // ---- inner: 4 k-steps x (6 ds_read_b128 + 6 MFMA) ----
        #pragma unroll
        for (int ks = 0; ks < 4; ++ks) {
            const int sb = ks * 4 + kq;              // slot index for this lane
            const int so = (sb ^ fm) * 8;            // swizzled short offset
            const short8 ah  = *(const short8*)&Ah[(m0 + fm) * RSTR + so];
            const short8 al  = *(const short8*)&Al[(m0 + fm) * RSTR + so];
            const short8 bh0 = *(const short8*)&Wh[(n0 + fm) * RSTR + so];
            const short8 bl0 = *(const short8*)&Wl[(n0 + fm) * RSTR + so];
            const short8 bh1 = *(const short8*)&Wh[(n0 + 16 + fm) * RSTR + so];
            const short8 bl1 = *(const short8*)&Wl[(n0 + 16 + fm) * RSTR + so];
            acc0 = __builtin_amdgcn_mfma_f32_16x16x32_bf16(ah, bh0, acc0, 0, 0, 0);
            acc1 = __builtin_amdgcn_mfma_f32_16x16x32_bf16(ah, bh1, acc1, 0, 0, 0);
            acc0 = __builtin_amdgcn_mfma_f32_16x16x32_bf16(ah, bl0, acc0, 0, 0, 0);
            acc1 = __builtin_amdgcn_mfma_f32_16x16x32_bf16(ah, bl1, acc1, 0, 0, 0);
            acc0 = __builtin_amdgcn_mfma_f32_16x16x32_bf16(al, bh0, acc0, 0, 0, 0);
            acc1 = __builtin_amdgcn_mfma_f32_16x16x32_bf16(al, bh1, acc1, 0, 0, 0);
        }
    }

    // ---- epilogue: C/D layout col=lane&15, row=(lane>>4)*4+reg (m89) ----
    const int rbase = tile_r + m0 + kq * 4;
    const int c0 = tile_c + n0 + fm;
    const int c1 = c0 + 16;
    const float b0 = bias[c0], b1 = bias[c1];
    #pragma unroll
    for (int reg = 0; reg < 4; ++reg) {
        const int row = rbase + reg;
        const int n  = row & 3;
        const int li = (row >> 2) & 31;
        const float scale = (n == 0 || (n == 1 && li >= 16)) ? 1.0f : COEF;
        out[(size_t)row * COLS + c0] = tanh_fast(scale * acc0[reg] + b0);
        out[(size_t)row * COLS + c1] = tanh_fast(scale * acc1[reg] + b1);
    }
}

extern "C" void kernel_launch(void* const* d_in, const int* in_sizes, int n_in,
                              void* d_out, int out_size, void* d_ws, size_t ws_size,
                              hipStream_t stream) {
    const float* enc  = (const float*)d_in[0];   // [32, 512, 1024]
    const float* W    = (const float*)d_in[1];   // [256, 256]
    const float* bias = (const float*)d_in[2];   // [256]
    float* out = (float*)d_out;                  // [32, 32, 4, 256]

    dim3 grid(ROWS / TR, COLS / TC);             // 128 x 4 = 512 blocks
    spectral_mfma_kernel<<<grid, dim3(256), 0, stream>>>(enc, W, bias, out);
}

// Round 8
// 93.190 us; speedup vs baseline: 1.4114x; 1.0057x over previous
//
#include <hip/hip_runtime.h>
#include <math.h>

// Problem constants
#define LSEQ   512
#define DDIM   1024
#define KDIM   256       // K
#define COLS   256       // LATENT
#define ROWS   4096      // B * NTOK * NSEC
#define COEF   0.1f

// GEMM tiling: block 32 rows x 64 cols, 4 waves (wave = 16x32 strip, 2 MFMA
// tiles), full K=256 in ONE phase (one barrier). Grid 128x4 = 512 = 2/CU.
#define TR     32
#define TC     64

// Semantics collapse (verified R1-R7): spectral chain ==
//   out[row,o] = tanh( scale(row)*dot(enc_row, W[o,:]) + b[o] )
// R8: pre-convert enc(scaled)+W to bf16 ONCE (R7 split the same floats 512x
// inline, ~1.1us VALU/CU); single-pass bf16 MFMA (error ~8e-3 max << 2e-2);
// stage LDS via global_load_lds dwordx4 (zero VALU, zero ds_write; XOR swizzle
// done on the global source side - a permutation within each 512B row, still
// coalesced; LDS dest is wave-uniform base + lane*16 per m104/m108).
// Known-bad: fp32 LDS-LDS ~19.6us; global/scalar W inner loop 45-47us;
// 3-pass split bf16 ~12us.

typedef __attribute__((ext_vector_type(8))) short short8;    // 8 bf16 frag
typedef __attribute__((ext_vector_type(4))) float float4v;   // MFMA C/D
typedef __attribute__((ext_vector_type(4))) short short4v;

__device__ __forceinline__ float tanh_fast(float x) {
    // 1 - 2/(e^{2x}+1): exact +/-inf limits, ~1e-6 abs err via v_exp_f32
    return 1.0f - 2.0f / (__expf(2.0f * x) + 1.0f);
}

__device__ __forceinline__ unsigned short bf16_rne(float x) {
    union { float f; unsigned u; } v; v.f = x;
    return (unsigned short)((v.u + 0x7fffu + ((v.u >> 16) & 1u)) >> 16);
}

// enc rows (l<32, row-scale folded) -> Ab bf16[4096][256]; W -> Wb bf16[256][256]
__global__ __launch_bounds__(256, 8)
void convert_kernel(const float* __restrict__ enc, const float* __restrict__ W,
                    unsigned short* __restrict__ Ab, unsigned short* __restrict__ Wb) {
    const int e = (blockIdx.x * 256 + threadIdx.x) * 4;
    if (e < ROWS * KDIM) {
        const int r = e >> 8;
        const int n = r & 3, l = (r >> 2) & 31;
        const float scale = (n == 0 || (n == 1 && l >= 16)) ? 1.0f : COEF;
        const float4 v = *(const float4*)(enc + (size_t)(r >> 7) * (size_t)(LSEQ * DDIM)
                                              + (size_t)(r & 127) * KDIM + (e & 255));
        short4v o;
        o.x = (short)bf16_rne(v.x * scale);
        o.y = (short)bf16_rne(v.y * scale);
        o.z = (short)bf16_rne(v.z * scale);
        o.w = (short)bf16_rne(v.w * scale);
        *(short4v*)(Ab + e) = o;
    } else {
        const int ew = e - ROWS * KDIM;
        const float4 v = *(const float4*)(W + ew);
        short4v o;
        o.x = (short)bf16_rne(v.x); o.y = (short)bf16_rne(v.y);
        o.z = (short)bf16_rne(v.z); o.w = (short)bf16_rne(v.w);
        *(short4v*)(Wb + ew) = o;
    }
}

__global__ __launch_bounds__(256, 2)
void spectral_mfma_kernel(const unsigned short* __restrict__ Ab,
                          const unsigned short* __restrict__ Wb,
                          const float* __restrict__ bias,
                          float* __restrict__ out) {
    // shorts; A rows at [0, 8192) (32 x 256), W rows at [8192, 24576) (64 x 256)
    // stored[r][p] = logical[r][p ^ (r&15)] (16B slots) -> conflict-free b128.
    __shared__ unsigned short SH[24576];   // 48 KB

    const int t    = threadIdx.x;
    const int lane = t & 63;
    const int wv   = t >> 6;
    const int tile_r = blockIdx.x * TR;    // 32 | 128: no batch-segment straddle
    const int tile_c = blockIdx.y * TC;

    // ---- stage 48 KB via 12 global_load_lds_dwordx4 per wave-group ----
    #pragma unroll
    for (int i = 0; i < 12; ++i) {
        const int c = wv + i * 4;          // wave-uniform chunk id, 0..47
        const unsigned short* src;
        if (c < 16) {                      // A: 1024 slots of 16B
            const int q = c * 64 + lane;
            const int r = q >> 5, p = q & 31;
            src = Ab + (size_t)(tile_r + r) * KDIM + ((p ^ (r & 15)) * 8);
        } else {                           // W: 2048 slots
            const int q = (c - 16) * 64 + lane;
            const int r = q >> 5, p = q & 31;
            src = Wb + (size_t)(tile_c + r) * KDIM + ((p ^ (r & 15)) * 8);
        }
        __builtin_amdgcn_global_load_lds(
            (const __attribute__((address_space(1))) unsigned int*)src,
            (__attribute__((address_space(3))) unsigned int*)&SH[c * 512],
            16, 0, 0);
    }
    __syncthreads();                       // drains vmcnt then barrier

    const int fm = lane & 15;              // frag row/col AND swizzle key
    const int kq = lane >> 4;              // k-quad
    const int m0 = (wv & 1) * 16;
    const int n0 = (wv >> 1) * 32;

    const int arow  = (m0 + fm) * 256;
    const int wrow0 = 8192 + (n0 + fm) * 256;
    const int wrow1 = wrow0 + 16 * 256;

    float4v acc0 = {0.f, 0.f, 0.f, 0.f};
    float4v acc1 = {0.f, 0.f, 0.f, 0.f};

    // ---- inner: 8 k-steps x (3 ds_read_b128 + 2 MFMA), one barrier total ----
    #pragma unroll
    for (int ks = 0; ks < 8; ++ks) {
        const int so = ((ks * 4 + kq) ^ fm) * 8;   // swizzled short offset
        const short8 a  = *(const short8*)&SH[arow + so];
        const short8 b0 = *(const short8*)&SH[wrow0 + so];
        const short8 b1 = *(const short8*)&SH[wrow1 + so];
        acc0 = __builtin_amdgcn_mfma_f32_16x16x32_bf16(a, b0, acc0, 0, 0, 0);
        acc1 = __builtin_amdgcn_mfma_f32_16x16x32_bf16(a, b1, acc1, 0, 0, 0);
    }

    // ---- epilogue: bias + tanh (scale already folded into Ab) ----
    // C/D layout: col = lane&15, row = (lane>>4)*4 + reg   (m89)
    const int rbase = tile_r + m0 + kq * 4;
    const int c0 = tile_c + n0 + fm;
    const int c1 = c0 + 16;
    const float b0 = bias[c0], b1 = bias[c1];
    #pragma unroll
    for (int reg = 0; reg < 4; ++reg) {
        const int row = rbase + reg;
        out[(size_t)row * COLS + c0] = tanh_fast(acc0[reg] + b0);
        out[(size_t)row * COLS + c1] = tanh_fast(acc1[reg] + b1);
    }
}

extern "C" void kernel_launch(void* const* d_in, const int* in_sizes, int n_in,
                              void* d_out, int out_size, void* d_ws, size_t ws_size,
                              hipStream_t stream) {
    const float* enc  = (const float*)d_in[0];   // [32, 512, 1024]
    const float* W    = (const float*)d_in[1];   // [256, 256]
    const float* bias = (const float*)d_in[2];   // [256]
    float* out = (float*)d_out;                  // [32, 32, 4, 256]

    unsigned short* Ab = (unsigned short*)d_ws;          // [4096][256] bf16
    unsigned short* Wb = Ab + ROWS * KDIM;               // [256][256] bf16

    // (ROWS*KDIM + COLS*KDIM) / 4 / 256 = 1088 blocks exactly
    convert_kernel<<<dim3(1088), dim3(256), 0, stream>>>(enc, W, Ab, Wb);

    dim3 grid(ROWS / TR, COLS / TC);                     // 128 x 4 = 512 blocks
    spectral_mfma_kernel<<<grid, dim3(256), 0, stream>>>(Ab, Wb, bias, out);
}

// Round 9
// 91.358 us; speedup vs baseline: 1.4397x; 1.0200x over previous
//
#include <hip/hip_runtime.h>
#include <hip/hip_bf16.h>
#include <math.h>

// Problem constants
#define LSEQ   512
#define DDIM   1024
#define KDIM   256       // K
#define COLS   256       // LATENT
#define ROWS   4096      // B * NTOK * NSEC
#define COEF   0.1f

// Tiling: block 32 rows x 64 cols, 4 waves (wave = 16x32 strip, 2 MFMA tiles),
// full K=256 in ONE phase, ONE barrier. Grid 128x4 = 512 blocks = 2/CU.
#define TR     32
#define TC     64

// Semantics collapse (verified R1-R8): spectral chain ==
//   out[row,o] = tanh( scale(row)*dot(enc_row, W[o,:]) + b[o] )
// R9: single fused kernel. Inline fp32->bf16 via v_cvt_pk_bf16_f32
// (__float22bfloat162_rn, 1 VALU / 2 floats) -- R7's manual 3-pass split cost
// ~10 VALU/float and 3x the MFMA/reads; R8's separate convert kernel paid the
// savings back in launch + ws round-trip (93.7 vs 93.2). Row-scale applied in
// the epilogue. 1-pass bf16 verified safe: R8 absmax 0.0103 < 2e-2.
// LDS: 16B slot = one 8-bf16 MFMA frag; stored[r][p] = logical[r][p ^ (r&15)]
// -> conflict-free b128 reads and writes, zero padding, 48 KB, one barrier.
// Known-bad: fp32 LDS-LDS (~19.6us); global/scalar W inner loop (45-47us);
// 1 wave/SIMD (R6); inline Dekker split (R7); 2-kernel bf16 (R8).

typedef __attribute__((ext_vector_type(8))) short short8;    // 8 bf16 frag
typedef __attribute__((ext_vector_type(4))) float float4v;   // MFMA C/D

__device__ __forceinline__ float tanh_fast(float x) {
    // 1 - 2/(e^{2x}+1): exact +/-inf limits, ~1e-6 abs err via v_exp_f32
    return 1.0f - 2.0f / (__expf(2.0f * x) + 1.0f);
}

__device__ __forceinline__ uint4 pack8_bf16(const float4 x0, const float4 x1) {
    union { __hip_bfloat162 h2[4]; uint4 u4; } pk;
    pk.h2[0] = __float22bfloat162_rn(make_float2(x0.x, x0.y));  // k0 low, k1 high
    pk.h2[1] = __float22bfloat162_rn(make_float2(x0.z, x0.w));
    pk.h2[2] = __float22bfloat162_rn(make_float2(x1.x, x1.y));
    pk.h2[3] = __float22bfloat162_rn(make_float2(x1.z, x1.w));
    return pk.u4;
}

__global__ __launch_bounds__(256, 2)
void spectral_mfma_kernel(const float* __restrict__ enc,
                          const float* __restrict__ W,
                          const float* __restrict__ bias,
                          float* __restrict__ out) {
    // shorts; A rows at [0,8192) (32 x 256), W rows at [8192,24576) (64 x 256)
    __shared__ unsigned short SH[24576];   // 48 KB

    const int t    = threadIdx.x;
    const int lane = t & 63;
    const int wv   = t >> 6;
    const int tile_r = blockIdx.x * TR;    // 32 | 128: no batch-segment straddle
    const int tile_c = blockIdx.y * TC;

    const float* __restrict__ srcA = enc + (size_t)(tile_r >> 7) * (size_t)(LSEQ * DDIM)
                                         + (size_t)(tile_r & 127) * KDIM;
    const float* __restrict__ srcW = W + (size_t)tile_c * KDIM;

    // ---- stage A: 1024 slots (32 rows x 32), 4 per thread ----
    #pragma unroll
    for (int i = 0; i < 4; ++i) {
        const int q = t + i * 256;
        const int r = q >> 5, s = q & 31;
        const float* g = srcA + (size_t)r * KDIM + s * 8;
        const uint4 v = pack8_bf16(*(const float4*)g, *(const float4*)(g + 4));
        *(uint4*)&SH[(r * 32 + (s ^ (r & 15))) * 8] = v;
    }
    // ---- stage W: 2048 slots (64 rows x 32), 8 per thread ----
    #pragma unroll
    for (int i = 0; i < 8; ++i) {
        const int q = t + i * 256;
        const int r = q >> 5, s = q & 31;
        const float* g = srcW + (size_t)r * KDIM + s * 8;
        const uint4 v = pack8_bf16(*(const float4*)g, *(const float4*)(g + 4));
        *(uint4*)&SH[8192 + (r * 32 + (s ^ (r & 15))) * 8] = v;
    }
    __syncthreads();

    const int fm = lane & 15;              // frag row/col AND swizzle key
    const int kq = lane >> 4;              // k-quad
    const int m0 = (wv & 1) * 16;
    const int n0 = (wv >> 1) * 32;

    const int arow  = (m0 + fm) * 256;
    const int wrow0 = 8192 + (n0 + fm) * 256;
    const int wrow1 = wrow0 + 16 * 256;

    float4v acc0 = {0.f, 0.f, 0.f, 0.f};
    float4v acc1 = {0.f, 0.f, 0.f, 0.f};

    // ---- inner: 8 k-steps x (3 ds_read_b128 + 2 MFMA), one barrier total ----
    #pragma unroll
    for (int ks = 0; ks < 8; ++ks) {
        const int so = ((ks * 4 + kq) ^ fm) * 8;   // swizzled short offset
        const short8 a  = *(const short8*)&SH[arow + so];
        const short8 b0 = *(const short8*)&SH[wrow0 + so];
        const short8 b1 = *(const short8*)&SH[wrow1 + so];
        acc0 = __builtin_amdgcn_mfma_f32_16x16x32_bf16(a, b0, acc0, 0, 0, 0);
        acc1 = __builtin_amdgcn_mfma_f32_16x16x32_bf16(a, b1, acc1, 0, 0, 0);
    }

    // ---- epilogue: scale + bias + tanh ----
    // C/D layout: col = lane&15, row = (lane>>4)*4 + reg   (m89)
    const int rbase = tile_r + m0 + kq * 4;
    const int c0 = tile_c + n0 + fm;
    const int c1 = c0 + 16;
    const float b0 = bias[c0], b1 = bias[c1];
    #pragma unroll
    for (int reg = 0; reg < 4; ++reg) {
        const int row = rbase + reg;
        const int n  = row & 3;
        const int li = (row >> 2) & 31;
        const float scale = (n == 0 || (n == 1 && li >= 16)) ? 1.0f : COEF;
        out[(size_t)row * COLS + c0] = tanh_fast(scale * acc0[reg] + b0);
        out[(size_t)row * COLS + c1] = tanh_fast(scale * acc1[reg] + b1);
    }
}

extern "C" void kernel_launch(void* const* d_in, const int* in_sizes, int n_in,
                              void* d_out, int out_size, void* d_ws, size_t ws_size,
                              hipStream_t stream) {
    const float* enc  = (const float*)d_in[0];   // [32, 512, 1024]
    const float* W    = (const float*)d_in[1];   // [256, 256]
    const float* bias = (const float*)d_in[2];   // [256]
    float* out = (float*)d_out;                  // [32, 32, 4, 256]

    dim3 grid(ROWS / TR, COLS / TC);             // 128 x 4 = 512 blocks
    spectral_mfma_kernel<<<grid, dim3(256), 0, stream>>>(enc, W, bias, out);
}